// Round 2
// baseline (1151.089 us; speedup 1.0000x reference)
//
#include <hip/hip_runtime.h>
#include <hip/hip_bf16.h>
#include <cstdint>
#include <cstddef>

// Problem constants (PropSTGformer)
#define B_   4
#define T_   24
#define NN_  2048
#define D_   256
#define H_   8
#define HD_  32
#define BT_  (B_*T_)           // 96
#define MTOK (B_*T_*NN_)       // 196608 tokens

using bf16 = __hip_bfloat16;

typedef __attribute__((ext_vector_type(8))) short bf16x8;   // MFMA A/B frag (4 VGPRs)
typedef __attribute__((ext_vector_type(4))) float f32x4;    // MFMA C/D frag

__device__ __forceinline__ float bf2f(bf16 v) { return __bfloat162float(v); }
__device__ __forceinline__ ushort f2bfu(float x) {
  bf16 t = __float2bfloat16(x);
  return *(ushort*)&t;
}

// async global->LDS, 16B per lane. LDS dest must be wave-uniform base (+lane*16 implicit).
__device__ __forceinline__ void async_copy16(const void* g, void* l) {
  __builtin_amdgcn_global_load_lds(
      (const __attribute__((address_space(1))) void*)g,
      (__attribute__((address_space(3))) void*)l,
      16, 0, 0);
}

// sum over the 32-lane half-wave group (all lanes get result)
__device__ __forceinline__ float red32(float v) {
  v += __shfl_xor(v, 1, 64);
  v += __shfl_xor(v, 2, 64);
  v += __shfl_xor(v, 4, 64);
  v += __shfl_xor(v, 8, 64);
  v += __shfl_xor(v, 16, 64);
  return v;
}

// unpack 8 bf16 (one uint4) and FMA against col[m0..m0+7]; also accumulate row sum
#define UNPK8(u, F0,F1,F2,F3,F4,F5,F6,F7)                       \
  const float F0 = __uint_as_float((u).x << 16);                \
  const float F1 = __uint_as_float((u).x & 0xffff0000u);        \
  const float F2 = __uint_as_float((u).y << 16);                \
  const float F3 = __uint_as_float((u).y & 0xffff0000u);        \
  const float F4 = __uint_as_float((u).z << 16);                \
  const float F5 = __uint_as_float((u).z & 0xffff0000u);        \
  const float F6 = __uint_as_float((u).w << 16);                \
  const float F7 = __uint_as_float((u).w & 0xffff0000u);

// ---------------------------------------------------------------- convert f32 -> bf16
__global__ void k_convert(const float* __restrict__ in, bf16* __restrict__ out, int n4) {
  int i = blockIdx.x * blockDim.x + threadIdx.x;
  if (i < n4) {
    float4 v = ((const float4*)in)[i];
    bf16 t[4] = {__float2bfloat16(v.x), __float2bfloat16(v.y),
                 __float2bfloat16(v.z), __float2bfloat16(v.w)};
    ((ushort4*)out)[i] = *(ushort4*)t;
  }
}

// ---------------------------------------------------------------- bf16 GEMM, C = A * Bw^T
// A: [M x KD] row-major bf16. Bw: [ncols x KD] row-major bf16 (i.e. B[k][n] = Bw[n][k]).
// 128x128 tile, BK=64, 4 waves each computing 64x64 (4x4 tiles of 16x16x32 MFMA).
template<int KD, bool OUTF32>
__global__ __launch_bounds__(256, 2)
void k_gemm(const bf16* __restrict__ A, const bf16* __restrict__ Bw,
            void* __restrict__ Cout, const float* __restrict__ bias, int ncols) {
  __shared__ bf16 As[128 * 64];
  __shared__ bf16 Bs[128 * 64];
  const int tid  = threadIdx.x;
  const int wave = tid >> 6, lane = tid & 63;
  const int quad = lane >> 4, l16 = lane & 15;
  const long row0 = (long)blockIdx.x * 128;
  const long col0 = (long)blockIdx.y * 128;
  const int wm = (wave & 1) * 64, wn = (wave >> 1) * 64;
  const int srow = lane >> 3;          // row within 8-row staging chunk
  const int skb  = (lane & 7) * 8;     // k-element offset (8 bf16 = 16B)

  f32x4 acc[4][4];
  const f32x4 z = {0.f, 0.f, 0.f, 0.f};
#pragma unroll
  for (int a = 0; a < 4; ++a)
#pragma unroll
    for (int b = 0; b < 4; ++b) acc[a][b] = z;

  for (int k0 = 0; k0 < KD; k0 += 64) {
#pragma unroll
    for (int i = 0; i < 4; ++i) {
      const int c = wave * 4 + i;          // chunk id, wave-uniform
      const int r = c * 8 + srow;          // tile row
      async_copy16(A  + (row0 + r) * KD + k0 + skb, (char*)As + c * 1024);
      async_copy16(Bw + (col0 + r) * KD + k0 + skb, (char*)Bs + c * 1024);
    }
    __syncthreads();
#pragma unroll
    for (int kk = 0; kk < 64; kk += 32) {
      bf16x8 af[4], bfr[4];
#pragma unroll
      for (int i = 0; i < 4; ++i)
        af[i] = *(const bf16x8*)(As + (wm + i * 16 + l16) * 64 + kk + quad * 8);
#pragma unroll
      for (int i = 0; i < 4; ++i)
        bfr[i] = *(const bf16x8*)(Bs + (wn + i * 16 + l16) * 64 + kk + quad * 8);
#pragma unroll
      for (int mi = 0; mi < 4; ++mi)
#pragma unroll
        for (int ni = 0; ni < 4; ++ni)
          acc[mi][ni] = __builtin_amdgcn_mfma_f32_16x16x32_bf16(af[mi], bfr[ni], acc[mi][ni], 0, 0, 0);
    }
    __syncthreads();
  }

  // epilogue: C/D layout col=lane&15, row=quad*4+reg
#pragma unroll
  for (int mi = 0; mi < 4; ++mi)
#pragma unroll
    for (int ni = 0; ni < 4; ++ni) {
      const long colg = col0 + wn + ni * 16 + l16;
#pragma unroll
      for (int r = 0; r < 4; ++r) {
        const long rowg = row0 + wm + mi * 16 + quad * 4 + r;
        const float v = acc[mi][ni][r];
        if (OUTF32) {
          ((float*)Cout)[rowg * ncols + colg] = v + bias[colg];
        } else {
          ((bf16*)Cout)[rowg * ncols + colg] = __float2bfloat16(v);
        }
      }
    }
}

// ---------------------------------------------------------------- spatial stats
// per (bt, h): kvs[m][d] = sum_n khat[n][m]*v[n][d]  (32x32), ks_sum[m] = sum_n khat[n][m]
// stats layout: [bt][h][1056] = 1024 kvs + 32 ks_sum, fp32
// ALSO writes khat (bf16) back in-place over the k slot of qkv (consumed by temporal).
__global__ __launch_bounds__(256)
void k_spatial_stats(bf16* __restrict__ qkv, float* __restrict__ stats) {
  const int bt = blockIdx.x, h = blockIdx.y;
  const int tid = threadIdx.x;
  const int wave = tid >> 6, lane = tid & 63;
  __shared__ float lk[256][36];   // khat, token-major, +pad
  __shared__ float lv[256][36];   // v
  const int mg = lane >> 3, dg = lane & 7;
  const int m0 = mg * 4, d0 = dg * 4;
  float acc[4][4] = {};
  float ssum[4] = {0.f, 0.f, 0.f, 0.f};

  for (int c = wave * 64; c < NN_; c += 256) {
    const size_t row = ((size_t)bt * NN_ + c + lane) * 768;
    bf16 kb[32], vb[32];
    const uint4* kp = (const uint4*)(qkv + row + 256 + h * 32);
    const uint4* vp = (const uint4*)(qkv + row + 512 + h * 32);
#pragma unroll
    for (int j = 0; j < 4; ++j) { ((uint4*)kb)[j] = kp[j]; ((uint4*)vb)[j] = vp[j]; }
    float kf[32]; float ss = 0.f;
#pragma unroll
    for (int j = 0; j < 32; ++j) { kf[j] = bf2f(kb[j]); ss += kf[j] * kf[j]; }
    const float sc = 1.f / fmaxf(sqrtf(ss), 1e-12f);
#pragma unroll
    for (int j = 0; j < 32; ++j) kf[j] *= sc;
    // write khat back (bf16, 64B per token-head)
    ushort kh16[32];
#pragma unroll
    for (int j = 0; j < 32; ++j) kh16[j] = f2bfu(kf[j]);
    uint4* dstk = (uint4*)(qkv + row + 256 + h * 32);
#pragma unroll
    for (int j = 0; j < 4; ++j) dstk[j] = ((uint4*)kh16)[j];

    float vf[32];
#pragma unroll
    for (int j = 0; j < 32; ++j) vf[j] = bf2f(vb[j]);
    const int lrow = wave * 64 + lane;
#pragma unroll
    for (int j = 0; j < 8; ++j) {
      ((float4*)lk[lrow])[j] = ((float4*)kf)[j];
      ((float4*)lv[lrow])[j] = ((float4*)vf)[j];
    }
    __syncthreads();
#pragma unroll 2
    for (int t = 0; t < 64; ++t) {
      const int tr = wave * 64 + t;
      const float4 ka = *(const float4*)&lk[tr][m0];   // broadcast within wave (free)
      const float4 va = *(const float4*)&lv[tr][d0];
      const float km[4] = {ka.x, ka.y, ka.z, ka.w};
      const float vm[4] = {va.x, va.y, va.z, va.w};
#pragma unroll
      for (int i = 0; i < 4; ++i) {
        ssum[i] += km[i];
#pragma unroll
        for (int j = 0; j < 4; ++j) acc[i][j] += km[i] * vm[j];
      }
    }
    __syncthreads();
  }

  // cross-wave reduction via LDS (reuse lk storage: 4 x 1056 floats)
  float* rbuf = (float*)lk;
  float* wb = rbuf + wave * 1056;
#pragma unroll
  for (int i = 0; i < 4; ++i) {
    float4 o = {acc[i][0], acc[i][1], acc[i][2], acc[i][3]};
    *(float4*)&wb[(m0 + i) * 32 + d0] = o;
  }
  if (dg == 0) {
#pragma unroll
    for (int i = 0; i < 4; ++i) wb[1024 + m0 + i] = ssum[i];
  }
  __syncthreads();
  float* base = stats + ((size_t)bt * H_ + h) * 1056;
  for (int e = tid; e < 1056; e += 256)
    base[e] = rbuf[e] + rbuf[1056 + e] + rbuf[2112 + e] + rbuf[3168 + e];
}

// ---------------------------------------------------------------- spatial output (v3)
// block = (32-token chunk c, bt); thread = (h, d).
// kvs column [m][d] + full ks_sum[32] in registers; qhat rows staged bf16 in LDS
// (4x ds_read_b128 broadcast per row); den fused into the num FMA loop (no den red32).
// ALSO writes qhat (bf16) back in-place over the q slot of qkv (consumed by temporal).
#define TCH 32
__global__ __launch_bounds__(256, 3)
void k_spatial_out(bf16* __restrict__ qkv, const float* __restrict__ stats,
                   bf16* __restrict__ concat) {
  const int c  = blockIdx.x;
  const int bt = blockIdx.y;
  const int tid = threadIdx.x;
  const int h = tid >> 5, d = tid & 31;
  __shared__ uint4 qrow4[TCH * 8 * 4];   // row (tok, h) = 64B of bf16; 16 KB

  const float* sbase = stats + ((size_t)bt * H_ + h) * 1056;
  float kvcol[32];
#pragma unroll
  for (int m = 0; m < 32; ++m) kvcol[m] = sbase[m * 32 + d];
  float kss[32];
#pragma unroll
  for (int j = 0; j < 8; ++j) ((float4*)kss)[j] = ((const float4*)(sbase + 1024))[j];

  const size_t tok0 = (size_t)bt * NN_ + (size_t)c * TCH;

  // phase 1: per-token L2 norm of q (one red32 each); bf16 row -> LDS + global writeback
  for (int i = 0; i < TCH; i += 8) {
    float qf[8];
#pragma unroll
    for (int j = 0; j < 8; ++j)
      qf[j] = bf2f(qkv[(tok0 + i + j) * 768 + h * 32 + d]);
#pragma unroll
    for (int j = 0; j < 8; ++j) {
      const float qss = red32(qf[j] * qf[j]);
      const float qn = qf[j] * (1.f / fmaxf(sqrtf(qss), 1e-12f));
      const ushort qb = f2bfu(qn);
      ((ushort*)qrow4)[((i + j) * 8 + h) * 32 + d] = qb;
      ((ushort*)qkv)[(tok0 + i + j) * 768 + h * 32 + d] = qb;
    }
  }
  __syncthreads();

  // phase 2: num = qhat_row . kvcol, den = qhat_row . kss (fused), broadcast LDS reads
  for (int i = 0; i < TCH; i += 8) {
    float vf8[8];
#pragma unroll
    for (int j = 0; j < 8; ++j)
      vf8[j] = bf2f(qkv[(tok0 + i + j) * 768 + 512 + h * 32 + d]);
#pragma unroll
    for (int j = 0; j < 8; ++j) {
      const uint4* r4 = qrow4 + ((i + j) * 8 + h) * 4;
      float num = 2048.f * vf8[j];
      float den = 2048.f;
#pragma unroll
      for (int cc = 0; cc < 4; ++cc) {
        const uint4 u = r4[cc];
        const int m0 = cc * 8;
        UNPK8(u, f0, f1, f2, f3, f4, f5, f6, f7)
        num = fmaf(f0, kvcol[m0+0], num); den = fmaf(f0, kss[m0+0], den);
        num = fmaf(f1, kvcol[m0+1], num); den = fmaf(f1, kss[m0+1], den);
        num = fmaf(f2, kvcol[m0+2], num); den = fmaf(f2, kss[m0+2], den);
        num = fmaf(f3, kvcol[m0+3], num); den = fmaf(f3, kss[m0+3], den);
        num = fmaf(f4, kvcol[m0+4], num); den = fmaf(f4, kss[m0+4], den);
        num = fmaf(f5, kvcol[m0+5], num); den = fmaf(f5, kss[m0+5], den);
        num = fmaf(f6, kvcol[m0+6], num); den = fmaf(f6, kss[m0+6], den);
        num = fmaf(f7, kvcol[m0+7], num); den = fmaf(f7, kss[m0+7], den);
      }
      den = fmaxf(den, 1e-5f);
      concat[(tok0 + i + j) * 512 + h * 32 + d] = __float2bfloat16(num / den);
    }
  }
}

// ---------------------------------------------------------------- temporal attention + output (v3)
// block = (n, b); thread = (h, d). khat/qhat are PRE-NORMALIZED (written in-place by the
// spatial kernels) -> no norm red32s here. Rows staged as bf16 via global_load_lds
// (24 wave-instrs, coalesced 512B runs). kvcol[32] + kss[32] in registers; den fused
// into the num FMA loop. ZERO cross-lane ops in this kernel.
__global__ __launch_bounds__(256, 4)
void k_temporal_out(const bf16* __restrict__ qkv, bf16* __restrict__ concat) {
  const int n = blockIdx.x, b = blockIdx.y;
  const int tid = threadIdx.x;
  const int wave = tid >> 6, lane = tid & 63;
  const int h = tid >> 5, d = tid & 31;
  __shared__ uint4 rows4[384 * 4];   // 24 KB; row R = s*192 + t*8 + h (s: 0=khat,1=qhat), 64B each

  // stage khat+qhat rows: 384 rows x 64B; instr i covers rows [i*16, i*16+16)
  {
    const int rl = lane >> 2, p = lane & 3;
#pragma unroll
    for (int q = 0; q < 6; ++q) {
      const int i = wave * 6 + q;              // wave-uniform
      const int R = i * 16 + rl;
      const int s = (R >= 192) ? 1 : 0;
      const int tt = (R - s * 192) >> 3;
      const int hh = R & 7;
      const size_t tok = ((size_t)b * T_ + tt) * NN_ + n;
      const size_t e = tok * 768 + (s ? 0 : 256) + hh * 32 + p * 8;
      async_copy16(qkv + e, (char*)rows4 + i * 1024);
    }
  }

  // own v column (overlaps staging latency)
  const size_t basev = ((size_t)b * T_ * NN_ + n) * 768 + 512 + h * 32 + d;
  const size_t tstep = (size_t)NN_ * 768;
  float vf[T_];
#pragma unroll
  for (int t = 0; t < T_; ++t) vf[t] = bf2f(qkv[basev + t * tstep]);

  __syncthreads();

  // phase 2: kvcol[m] = sum_t khat[t][m]*v[t][d]; kss[m] = sum_t khat[t][m]
  float kvcol[32], kss[32];
#pragma unroll
  for (int m = 0; m < 32; ++m) { kvcol[m] = 0.f; kss[m] = 0.f; }
#pragma unroll
  for (int t = 0; t < T_; ++t) {
    const uint4* r4 = rows4 + (t * 8 + h) * 4;
    const float v = vf[t];
#pragma unroll
    for (int cc = 0; cc < 4; ++cc) {
      const uint4 u = r4[cc];
      const int m0 = cc * 8;
      UNPK8(u, f0, f1, f2, f3, f4, f5, f6, f7)
      kvcol[m0+0] = fmaf(f0, v, kvcol[m0+0]); kss[m0+0] += f0;
      kvcol[m0+1] = fmaf(f1, v, kvcol[m0+1]); kss[m0+1] += f1;
      kvcol[m0+2] = fmaf(f2, v, kvcol[m0+2]); kss[m0+2] += f2;
      kvcol[m0+3] = fmaf(f3, v, kvcol[m0+3]); kss[m0+3] += f3;
      kvcol[m0+4] = fmaf(f4, v, kvcol[m0+4]); kss[m0+4] += f4;
      kvcol[m0+5] = fmaf(f5, v, kvcol[m0+5]); kss[m0+5] += f5;
      kvcol[m0+6] = fmaf(f6, v, kvcol[m0+6]); kss[m0+6] += f6;
      kvcol[m0+7] = fmaf(f7, v, kvcol[m0+7]); kss[m0+7] += f7;
    }
  }

  // phase 3: num = qhat_row . kvcol + 24*v; den = qhat_row . kss + 24
#pragma unroll
  for (int t = 0; t < T_; ++t) {
    const uint4* r4 = rows4 + ((192 + t * 8 + h)) * 4;
    float num = 24.f * vf[t];
    float den = 24.f;
#pragma unroll
    for (int cc = 0; cc < 4; ++cc) {
      const uint4 u = r4[cc];
      const int m0 = cc * 8;
      UNPK8(u, f0, f1, f2, f3, f4, f5, f6, f7)
      num = fmaf(f0, kvcol[m0+0], num); den = fmaf(f0, kss[m0+0], den);
      num = fmaf(f1, kvcol[m0+1], num); den = fmaf(f1, kss[m0+1], den);
      num = fmaf(f2, kvcol[m0+2], num); den = fmaf(f2, kss[m0+2], den);
      num = fmaf(f3, kvcol[m0+3], num); den = fmaf(f3, kss[m0+3], den);
      num = fmaf(f4, kvcol[m0+4], num); den = fmaf(f4, kss[m0+4], den);
      num = fmaf(f5, kvcol[m0+5], num); den = fmaf(f5, kss[m0+5], den);
      num = fmaf(f6, kvcol[m0+6], num); den = fmaf(f6, kss[m0+6], den);
      num = fmaf(f7, kvcol[m0+7], num); den = fmaf(f7, kss[m0+7], den);
    }
    den = fmaxf(den, 1e-5f);
    const size_t tok = (size_t)(b * T_ + t) * NN_ + n;
    concat[tok * 512 + 256 + h * 32 + d] = __float2bfloat16(num / den);
  }
}

// ---------------------------------------------------------------- launch
extern "C" void kernel_launch(void* const* d_in, const int* in_sizes, int n_in,
                              void* d_out, int out_size, void* d_ws, size_t ws_size,
                              hipStream_t stream) {
  (void)in_sizes; (void)n_in; (void)out_size; (void)ws_size;
  const float* x     = (const float*)d_in[0];
  const float* w_qkv = (const float*)d_in[1];
  const float* w_out = (const float*)d_in[2];
  const float* b_out = (const float*)d_in[3];
  float* out = (float*)d_out;
  char* ws = (char*)d_ws;

  // workspace layout (bytes); concat aliases x_bf16 (dead after K1)
  bf16* concat = (bf16*)(ws);                       // 201,326,592 B (196608*512*2)
  bf16* xb     = (bf16*)(ws);                       // 100,663,296 B (aliased)
  bf16* qkv    = (bf16*)(ws + 201326592);           // 301,989,888 B
  float* stats = (float*)(ws + 503316480);          //   3,244,032 B
  bf16* wqkvb  = (bf16*)(ws + 506560512);           //     393,216 B
  bf16* woutb  = (bf16*)(ws + 506953728);           //     262,144 B
  // total: 507,215,872 B

  // converts
  k_convert<<<(MTOK * D_ / 4 + 255) / 256, 256, 0, stream>>>(x, xb, MTOK * D_ / 4);
  k_convert<<<(768 * 256 / 4 + 255) / 256, 256, 0, stream>>>(w_qkv, wqkvb, 768 * 256 / 4);
  k_convert<<<(256 * 512 / 4 + 255) / 256, 256, 0, stream>>>(w_out, woutb, 256 * 512 / 4);

  // qkv = x @ w_qkv^T   (M=196608, N=768, K=256)
  k_gemm<256, false><<<dim3(MTOK / 128, 768 / 128), 256, 0, stream>>>(xb, wqkvb, qkv, nullptr, 768);

  // spatial stats over N (also writes khat in-place)
  k_spatial_stats<<<dim3(BT_, H_), 256, 0, stream>>>(qkv, stats);

  // spatial output (also writes qhat in-place), then temporal (consumes khat/qhat)
  k_spatial_out<<<dim3(NN_ / TCH, BT_), 256, 0, stream>>>(qkv, stats, concat);
  k_temporal_out<<<dim3(NN_, B_), 256, 0, stream>>>(qkv, concat);

  // final: out = concat @ w_out^T + b_out   (M=196608, N=256, K=512)
  k_gemm<512, true><<<dim3(MTOK / 128, 256 / 128), 256, 0, stream>>>(concat, woutb, out, b_out, 256);
}

// Round 3
// 1041.051 us; speedup vs baseline: 1.1057x; 1.1057x over previous
//
#include <hip/hip_runtime.h>
#include <hip/hip_bf16.h>
#include <cstdint>
#include <cstddef>

// Problem constants (PropSTGformer)
#define B_   4
#define T_   24
#define NN_  2048
#define D_   256
#define H_   8
#define HD_  32
#define BT_  (B_*T_)           // 96
#define MTOK (B_*T_*NN_)       // 196608 tokens

using bf16 = __hip_bfloat16;

typedef __attribute__((ext_vector_type(8))) short bf16x8;   // MFMA A/B frag (4 VGPRs)
typedef __attribute__((ext_vector_type(4))) float f32x4;    // MFMA C/D frag

__device__ __forceinline__ float bf2f(bf16 v) { return __bfloat162float(v); }
__device__ __forceinline__ ushort f2bfu(float x) {
  bf16 t = __float2bfloat16(x);
  return *(ushort*)&t;
}
// fast 1/sqrt and 1/x (1-ulp HW approx; outputs land in bf16 so precision is ample)
__device__ __forceinline__ float rsq_fast(float ss) {
  return __builtin_amdgcn_rsqf(fmaxf(ss, 1e-24f));   // == 1/max(sqrt(ss),1e-12)
}
__device__ __forceinline__ float rcp_fast(float x) {
  return __builtin_amdgcn_rcpf(x);
}

// async global->LDS, 16B per lane. LDS dest must be wave-uniform base (+lane*16 implicit).
__device__ __forceinline__ void async_copy16(const void* g, void* l) {
  __builtin_amdgcn_global_load_lds(
      (const __attribute__((address_space(1))) void*)g,
      (__attribute__((address_space(3))) void*)l,
      16, 0, 0);
}

// sum over the 32-lane half-wave group (all lanes get result)
__device__ __forceinline__ float red32(float v) {
  v += __shfl_xor(v, 1, 64);
  v += __shfl_xor(v, 2, 64);
  v += __shfl_xor(v, 4, 64);
  v += __shfl_xor(v, 8, 64);
  v += __shfl_xor(v, 16, 64);
  return v;
}

// unpack 8 bf16 (one uint4)
#define UNPK8(u, F0,F1,F2,F3,F4,F5,F6,F7)                       \
  const float F0 = __uint_as_float((u).x << 16);                \
  const float F1 = __uint_as_float((u).x & 0xffff0000u);        \
  const float F2 = __uint_as_float((u).y << 16);                \
  const float F3 = __uint_as_float((u).y & 0xffff0000u);        \
  const float F4 = __uint_as_float((u).z << 16);                \
  const float F5 = __uint_as_float((u).z & 0xffff0000u);        \
  const float F6 = __uint_as_float((u).w << 16);                \
  const float F7 = __uint_as_float((u).w & 0xffff0000u);

// ---------------------------------------------------------------- convert f32 -> bf16
__global__ void k_convert(const float* __restrict__ in, bf16* __restrict__ out, int n4) {
  int i = blockIdx.x * blockDim.x + threadIdx.x;
  if (i < n4) {
    float4 v = ((const float4*)in)[i];
    bf16 t[4] = {__float2bfloat16(v.x), __float2bfloat16(v.y),
                 __float2bfloat16(v.z), __float2bfloat16(v.w)};
    ((ushort4*)out)[i] = *(ushort4*)t;
  }
}

// ---------------------------------------------------------------- bf16 GEMM, C = A * Bw^T
// A: [M x KD] row-major bf16. Bw: [ncols x KD] row-major bf16 (i.e. B[k][n] = Bw[n][k]).
// 128x128 tile, BK=64, 4 waves each computing 64x64 (4x4 tiles of 16x16x32 MFMA).
template<int KD, bool OUTF32>
__global__ __launch_bounds__(256, 2)
void k_gemm(const bf16* __restrict__ A, const bf16* __restrict__ Bw,
            void* __restrict__ Cout, const float* __restrict__ bias, int ncols) {
  __shared__ bf16 As[128 * 64];
  __shared__ bf16 Bs[128 * 64];
  const int tid  = threadIdx.x;
  const int wave = tid >> 6, lane = tid & 63;
  const int quad = lane >> 4, l16 = lane & 15;
  const long row0 = (long)blockIdx.x * 128;
  const long col0 = (long)blockIdx.y * 128;
  const int wm = (wave & 1) * 64, wn = (wave >> 1) * 64;
  const int srow = lane >> 3;          // row within 8-row staging chunk
  const int skb  = (lane & 7) * 8;     // k-element offset (8 bf16 = 16B)

  f32x4 acc[4][4];
  const f32x4 z = {0.f, 0.f, 0.f, 0.f};
#pragma unroll
  for (int a = 0; a < 4; ++a)
#pragma unroll
    for (int b = 0; b < 4; ++b) acc[a][b] = z;

  for (int k0 = 0; k0 < KD; k0 += 64) {
#pragma unroll
    for (int i = 0; i < 4; ++i) {
      const int c = wave * 4 + i;          // chunk id, wave-uniform
      const int r = c * 8 + srow;          // tile row
      async_copy16(A  + (row0 + r) * KD + k0 + skb, (char*)As + c * 1024);
      async_copy16(Bw + (col0 + r) * KD + k0 + skb, (char*)Bs + c * 1024);
    }
    __syncthreads();
#pragma unroll
    for (int kk = 0; kk < 64; kk += 32) {
      bf16x8 af[4], bfr[4];
#pragma unroll
      for (int i = 0; i < 4; ++i)
        af[i] = *(const bf16x8*)(As + (wm + i * 16 + l16) * 64 + kk + quad * 8);
#pragma unroll
      for (int i = 0; i < 4; ++i)
        bfr[i] = *(const bf16x8*)(Bs + (wn + i * 16 + l16) * 64 + kk + quad * 8);
#pragma unroll
      for (int mi = 0; mi < 4; ++mi)
#pragma unroll
        for (int ni = 0; ni < 4; ++ni)
          acc[mi][ni] = __builtin_amdgcn_mfma_f32_16x16x32_bf16(af[mi], bfr[ni], acc[mi][ni], 0, 0, 0);
    }
    __syncthreads();
  }

  // epilogue: C/D layout col=lane&15, row=quad*4+reg
#pragma unroll
  for (int mi = 0; mi < 4; ++mi)
#pragma unroll
    for (int ni = 0; ni < 4; ++ni) {
      const long colg = col0 + wn + ni * 16 + l16;
#pragma unroll
      for (int r = 0; r < 4; ++r) {
        const long rowg = row0 + wm + mi * 16 + quad * 4 + r;
        const float v = acc[mi][ni][r];
        if (OUTF32) {
          ((float*)Cout)[rowg * ncols + colg] = v + bias[colg];
        } else {
          ((bf16*)Cout)[rowg * ncols + colg] = __float2bfloat16(v);
        }
      }
    }
}

// ---------------------------------------------------------------- spatial stats
// per (bt, h): kvs[m][d] = sum_n khat[n][m]*v[n][d]  (32x32), ks_sum[m] = sum_n khat[n][m]
// stats layout: [bt][h][1056] = 1024 kvs + 32 ks_sum, fp32
// ALSO writes khat (bf16) back in-place over the k slot of qkv (consumed by temporal).
__global__ __launch_bounds__(256)
void k_spatial_stats(bf16* __restrict__ qkv, float* __restrict__ stats) {
  const int bt = blockIdx.x, h = blockIdx.y;
  const int tid = threadIdx.x;
  const int wave = tid >> 6, lane = tid & 63;
  __shared__ float lk[256][36];   // khat, token-major, +pad
  __shared__ float lv[256][36];   // v
  const int mg = lane >> 3, dg = lane & 7;
  const int m0 = mg * 4, d0 = dg * 4;
  float acc[4][4] = {};
  float ssum[4] = {0.f, 0.f, 0.f, 0.f};

  for (int c = wave * 64; c < NN_; c += 256) {
    const size_t row = ((size_t)bt * NN_ + c + lane) * 768;
    bf16 kb[32], vb[32];
    const uint4* kp = (const uint4*)(qkv + row + 256 + h * 32);
    const uint4* vp = (const uint4*)(qkv + row + 512 + h * 32);
#pragma unroll
    for (int j = 0; j < 4; ++j) { ((uint4*)kb)[j] = kp[j]; ((uint4*)vb)[j] = vp[j]; }
    float kf[32]; float ss = 0.f;
#pragma unroll
    for (int j = 0; j < 32; ++j) { kf[j] = bf2f(kb[j]); ss += kf[j] * kf[j]; }
    const float sc = rsq_fast(ss);
#pragma unroll
    for (int j = 0; j < 32; ++j) kf[j] *= sc;
    // write khat back (bf16, 64B per token-head)
    ushort kh16[32];
#pragma unroll
    for (int j = 0; j < 32; ++j) kh16[j] = f2bfu(kf[j]);
    uint4* dstk = (uint4*)(qkv + row + 256 + h * 32);
#pragma unroll
    for (int j = 0; j < 4; ++j) dstk[j] = ((uint4*)kh16)[j];

    float vf[32];
#pragma unroll
    for (int j = 0; j < 32; ++j) vf[j] = bf2f(vb[j]);
    const int lrow = wave * 64 + lane;
#pragma unroll
    for (int j = 0; j < 8; ++j) {
      ((float4*)lk[lrow])[j] = ((float4*)kf)[j];
      ((float4*)lv[lrow])[j] = ((float4*)vf)[j];
    }
    __syncthreads();
#pragma unroll 2
    for (int t = 0; t < 64; ++t) {
      const int tr = wave * 64 + t;
      const float4 ka = *(const float4*)&lk[tr][m0];   // broadcast within wave (free)
      const float4 va = *(const float4*)&lv[tr][d0];
      const float km[4] = {ka.x, ka.y, ka.z, ka.w};
      const float vm[4] = {va.x, va.y, va.z, va.w};
#pragma unroll
      for (int i = 0; i < 4; ++i) {
        ssum[i] += km[i];
#pragma unroll
        for (int j = 0; j < 4; ++j) acc[i][j] += km[i] * vm[j];
      }
    }
    __syncthreads();
  }

  // cross-wave reduction via LDS (reuse lk storage: 4 x 1056 floats)
  float* rbuf = (float*)lk;
  float* wb = rbuf + wave * 1056;
#pragma unroll
  for (int i = 0; i < 4; ++i) {
    float4 o = {acc[i][0], acc[i][1], acc[i][2], acc[i][3]};
    *(float4*)&wb[(m0 + i) * 32 + d0] = o;
  }
  if (dg == 0) {
#pragma unroll
    for (int i = 0; i < 4; ++i) wb[1024 + m0 + i] = ssum[i];
  }
  __syncthreads();
  float* base = stats + ((size_t)bt * H_ + h) * 1056;
  for (int e = tid; e < 1056; e += 256)
    base[e] = rbuf[e] + rbuf[1056 + e] + rbuf[2112 + e] + rbuf[3168 + e];
}

// ---------------------------------------------------------------- spatial output (v4)
// block = (32-token chunk c, bt); thread = (h, d).
// kvs column [m][d] + full ks_sum[32] in registers; qhat rows staged bf16 in LDS
// (4x ds_read_b128 broadcast per row); den fused into the num FMA loop.
// rsq/rcp fast paths replace sqrt+div chains.
// ALSO writes qhat (bf16) back in-place over the q slot of qkv (consumed by temporal).
#define TCH 32
__global__ __launch_bounds__(256, 3)
void k_spatial_out(bf16* __restrict__ qkv, const float* __restrict__ stats,
                   bf16* __restrict__ concat) {
  const int c  = blockIdx.x;
  const int bt = blockIdx.y;
  const int tid = threadIdx.x;
  const int h = tid >> 5, d = tid & 31;
  __shared__ uint4 qrow4[TCH * 8 * 4];   // row (tok, h) = 64B of bf16; 16 KB

  const float* sbase = stats + ((size_t)bt * H_ + h) * 1056;
  float kvcol[32];
#pragma unroll
  for (int m = 0; m < 32; ++m) kvcol[m] = sbase[m * 32 + d];
  float kss[32];
#pragma unroll
  for (int j = 0; j < 8; ++j) ((float4*)kss)[j] = ((const float4*)(sbase + 1024))[j];

  const size_t tok0 = (size_t)bt * NN_ + (size_t)c * TCH;
  // per-thread element base pointers (int offsets from here on)
  const bf16* qp = qkv + tok0 * 768 + h * 32 + d;           // q slot, own element
  const bf16* vp = qp + 512;                                // v slot, own element
  bf16* qwb = (bf16*)qp;                                    // qhat writeback
  bf16* cp  = concat + tok0 * 512 + h * 32 + d;             // spatial half of concat

  // phase 1: per-token L2 norm of q (one red32 each); bf16 row -> LDS + global writeback
  for (int i = 0; i < TCH; i += 8) {
    float qf[8];
#pragma unroll
    for (int j = 0; j < 8; ++j)
      qf[j] = bf2f(qp[(i + j) * 768]);
#pragma unroll
    for (int j = 0; j < 8; ++j) {
      const float qss = red32(qf[j] * qf[j]);
      const float qn = qf[j] * rsq_fast(qss);
      const ushort qb = f2bfu(qn);
      ((ushort*)qrow4)[((i + j) * 8 + h) * 32 + d] = qb;
      ((ushort*)qwb)[(i + j) * 768] = qb;
    }
  }
  __syncthreads();

  // phase 2: num = qhat_row . kvcol, den = qhat_row . kss (fused), broadcast LDS reads
  for (int i = 0; i < TCH; i += 8) {
    float vf8[8];
#pragma unroll
    for (int j = 0; j < 8; ++j)
      vf8[j] = bf2f(vp[(i + j) * 768]);
#pragma unroll
    for (int j = 0; j < 8; ++j) {
      const uint4* r4 = qrow4 + ((i + j) * 8 + h) * 4;
      float num = 2048.f * vf8[j];
      float den = 2048.f;
#pragma unroll
      for (int cc = 0; cc < 4; ++cc) {
        const uint4 u = r4[cc];
        const int m0 = cc * 8;
        UNPK8(u, f0, f1, f2, f3, f4, f5, f6, f7)
        num = fmaf(f0, kvcol[m0+0], num); den = fmaf(f0, kss[m0+0], den);
        num = fmaf(f1, kvcol[m0+1], num); den = fmaf(f1, kss[m0+1], den);
        num = fmaf(f2, kvcol[m0+2], num); den = fmaf(f2, kss[m0+2], den);
        num = fmaf(f3, kvcol[m0+3], num); den = fmaf(f3, kss[m0+3], den);
        num = fmaf(f4, kvcol[m0+4], num); den = fmaf(f4, kss[m0+4], den);
        num = fmaf(f5, kvcol[m0+5], num); den = fmaf(f5, kss[m0+5], den);
        num = fmaf(f6, kvcol[m0+6], num); den = fmaf(f6, kss[m0+6], den);
        num = fmaf(f7, kvcol[m0+7], num); den = fmaf(f7, kss[m0+7], den);
      }
      den = fmaxf(den, 1e-5f);
      cp[(i + j) * 512] = __float2bfloat16(num * rcp_fast(den));
    }
  }
}

// ---------------------------------------------------------------- temporal attention + output (v4)
// block = (n, b); thread = (h, d). khat/qhat are PRE-NORMALIZED (written in-place by the
// spatial kernels) -> no norm red32s here. Rows staged as bf16 via global_load_lds
// (24 wave-instrs, coalesced 512B runs). kvcol[32] + kss[32] in registers; den fused
// into the num FMA loop. ZERO cross-lane ops in this kernel.
// launch_bounds(256,2): needs ~112 VGPR live; (256,4) capped at 64 and SPILLED (R2 bug).
__global__ __launch_bounds__(256, 2)
void k_temporal_out(const bf16* __restrict__ qkv, bf16* __restrict__ concat) {
  const int n = blockIdx.x, b = blockIdx.y;
  const int tid = threadIdx.x;
  const int wave = tid >> 6, lane = tid & 63;
  const int h = tid >> 5, d = tid & 31;
  __shared__ uint4 rows4[384 * 4];   // 24 KB; row R = s*192 + t*8 + h (s: 0=khat,1=qhat), 64B each

  // stage khat+qhat rows: 384 rows x 64B; instr i covers rows [i*16, i*16+16)
  {
    const int rl = lane >> 2, p = lane & 3;
#pragma unroll
    for (int q = 0; q < 6; ++q) {
      const int i = wave * 6 + q;              // wave-uniform
      const int R = i * 16 + rl;
      const int s = (R >= 192) ? 1 : 0;
      const int tt = (R - s * 192) >> 3;
      const int hh = R & 7;
      const size_t tok = ((size_t)b * T_ + tt) * NN_ + n;
      const size_t e = tok * 768 + (s ? 0 : 256) + hh * 32 + p * 8;
      async_copy16(qkv + e, (char*)rows4 + i * 1024);
    }
  }

  // own v column (overlaps staging latency)
  const size_t basev = ((size_t)b * T_ * NN_ + n) * 768 + 512 + h * 32 + d;
  const size_t tstep = (size_t)NN_ * 768;
  float vf[T_];
#pragma unroll
  for (int t = 0; t < T_; ++t) vf[t] = bf2f(qkv[basev + t * tstep]);

  __syncthreads();

  // phase 2: kvcol[m] = sum_t khat[t][m]*v[t][d]; kss[m] = sum_t khat[t][m]
  float kvcol[32], kss[32];
#pragma unroll
  for (int m = 0; m < 32; ++m) { kvcol[m] = 0.f; kss[m] = 0.f; }
#pragma unroll
  for (int t = 0; t < T_; ++t) {
    const uint4* r4 = rows4 + (t * 8 + h) * 4;
    const float v = vf[t];
#pragma unroll
    for (int cc = 0; cc < 4; ++cc) {
      const uint4 u = r4[cc];
      const int m0 = cc * 8;
      UNPK8(u, f0, f1, f2, f3, f4, f5, f6, f7)
      kvcol[m0+0] = fmaf(f0, v, kvcol[m0+0]); kss[m0+0] += f0;
      kvcol[m0+1] = fmaf(f1, v, kvcol[m0+1]); kss[m0+1] += f1;
      kvcol[m0+2] = fmaf(f2, v, kvcol[m0+2]); kss[m0+2] += f2;
      kvcol[m0+3] = fmaf(f3, v, kvcol[m0+3]); kss[m0+3] += f3;
      kvcol[m0+4] = fmaf(f4, v, kvcol[m0+4]); kss[m0+4] += f4;
      kvcol[m0+5] = fmaf(f5, v, kvcol[m0+5]); kss[m0+5] += f5;
      kvcol[m0+6] = fmaf(f6, v, kvcol[m0+6]); kss[m0+6] += f6;
      kvcol[m0+7] = fmaf(f7, v, kvcol[m0+7]); kss[m0+7] += f7;
    }
  }

  // phase 3: num = qhat_row . kvcol + 24*v; den = qhat_row . kss + 24
#pragma unroll
  for (int t = 0; t < T_; ++t) {
    const uint4* r4 = rows4 + ((192 + t * 8 + h)) * 4;
    float num = 24.f * vf[t];
    float den = 24.f;
#pragma unroll
    for (int cc = 0; cc < 4; ++cc) {
      const uint4 u = r4[cc];
      const int m0 = cc * 8;
      UNPK8(u, f0, f1, f2, f3, f4, f5, f6, f7)
      num = fmaf(f0, kvcol[m0+0], num); den = fmaf(f0, kss[m0+0], den);
      num = fmaf(f1, kvcol[m0+1], num); den = fmaf(f1, kss[m0+1], den);
      num = fmaf(f2, kvcol[m0+2], num); den = fmaf(f2, kss[m0+2], den);
      num = fmaf(f3, kvcol[m0+3], num); den = fmaf(f3, kss[m0+3], den);
      num = fmaf(f4, kvcol[m0+4], num); den = fmaf(f4, kss[m0+4], den);
      num = fmaf(f5, kvcol[m0+5], num); den = fmaf(f5, kss[m0+5], den);
      num = fmaf(f6, kvcol[m0+6], num); den = fmaf(f6, kss[m0+6], den);
      num = fmaf(f7, kvcol[m0+7], num); den = fmaf(f7, kss[m0+7], den);
    }
    den = fmaxf(den, 1e-5f);
    const size_t tok = (size_t)(b * T_ + t) * NN_ + n;
    concat[tok * 512 + 256 + h * 32 + d] = __float2bfloat16(num * rcp_fast(den));
  }
}

// ---------------------------------------------------------------- launch
extern "C" void kernel_launch(void* const* d_in, const int* in_sizes, int n_in,
                              void* d_out, int out_size, void* d_ws, size_t ws_size,
                              hipStream_t stream) {
  (void)in_sizes; (void)n_in; (void)out_size; (void)ws_size;
  const float* x     = (const float*)d_in[0];
  const float* w_qkv = (const float*)d_in[1];
  const float* w_out = (const float*)d_in[2];
  const float* b_out = (const float*)d_in[3];
  float* out = (float*)d_out;
  char* ws = (char*)d_ws;

  // workspace layout (bytes); concat aliases x_bf16 (dead after K1)
  bf16* concat = (bf16*)(ws);                       // 201,326,592 B (196608*512*2)
  bf16* xb     = (bf16*)(ws);                       // 100,663,296 B (aliased)
  bf16* qkv    = (bf16*)(ws + 201326592);           // 301,989,888 B
  float* stats = (float*)(ws + 503316480);          //   3,244,032 B
  bf16* wqkvb  = (bf16*)(ws + 506560512);           //     393,216 B
  bf16* woutb  = (bf16*)(ws + 506953728);           //     262,144 B
  // total: 507,215,872 B

  // converts
  k_convert<<<(MTOK * D_ / 4 + 255) / 256, 256, 0, stream>>>(x, xb, MTOK * D_ / 4);
  k_convert<<<(768 * 256 / 4 + 255) / 256, 256, 0, stream>>>(w_qkv, wqkvb, 768 * 256 / 4);
  k_convert<<<(256 * 512 / 4 + 255) / 256, 256, 0, stream>>>(w_out, woutb, 256 * 512 / 4);

  // qkv = x @ w_qkv^T   (M=196608, N=768, K=256)
  k_gemm<256, false><<<dim3(MTOK / 128, 768 / 128), 256, 0, stream>>>(xb, wqkvb, qkv, nullptr, 768);

  // spatial stats over N (also writes khat in-place)
  k_spatial_stats<<<dim3(BT_, H_), 256, 0, stream>>>(qkv, stats);

  // spatial output (also writes qhat in-place), then temporal (consumes khat/qhat)
  k_spatial_out<<<dim3(NN_ / TCH, BT_), 256, 0, stream>>>(qkv, stats, concat);
  k_temporal_out<<<dim3(NN_, B_), 256, 0, stream>>>(qkv, concat);

  // final: out = concat @ w_out^T + b_out   (M=196608, N=256, K=512)
  k_gemm<512, true><<<dim3(MTOK / 128, 256 / 128), 256, 0, stream>>>(concat, woutb, out, b_out, 256);
}

// Round 5
// 1023.476 us; speedup vs baseline: 1.1247x; 1.0172x over previous
//
#include <hip/hip_runtime.h>
#include <hip/hip_bf16.h>
#include <cstdint>
#include <cstddef>

// Problem constants (PropSTGformer)
#define B_   4
#define T_   24
#define NN_  2048
#define D_   256
#define H_   8
#define HD_  32
#define BT_  (B_*T_)           // 96
#define MTOK (B_*T_*NN_)       // 196608 tokens

using bf16 = __hip_bfloat16;

typedef __attribute__((ext_vector_type(8))) short bf16x8;   // MFMA A/B frag (4 VGPRs)
typedef __attribute__((ext_vector_type(4))) float f32x4;    // MFMA C/D frag

__device__ __forceinline__ float bf2f(bf16 v) { return __bfloat162float(v); }
__device__ __forceinline__ ushort f2bfu(float x) {
  bf16 t = __float2bfloat16(x);
  return *(ushort*)&t;
}
__device__ __forceinline__ float bfu2f(ushort u) {
  return __uint_as_float((uint32_t)u << 16);
}
// fast 1/sqrt and 1/x (1-ulp HW approx; outputs land in bf16 so precision is ample)
__device__ __forceinline__ float rsq_fast(float ss) {
  return __builtin_amdgcn_rsqf(fmaxf(ss, 1e-24f));   // == 1/max(sqrt(ss),1e-12)
}
__device__ __forceinline__ float rcp_fast(float x) {
  return __builtin_amdgcn_rcpf(x);
}

// async global->LDS, 16B per lane. LDS dest must be wave-uniform base (+lane*16 implicit).
__device__ __forceinline__ void async_copy16(const void* g, void* l) {
  __builtin_amdgcn_global_load_lds(
      (const __attribute__((address_space(1))) void*)g,
      (__attribute__((address_space(3))) void*)l,
      16, 0, 0);
}

// unpack 8 bf16 (one uint4)
#define UNPK8(u, F0,F1,F2,F3,F4,F5,F6,F7)                       \
  const float F0 = __uint_as_float((u).x << 16);                \
  const float F1 = __uint_as_float((u).x & 0xffff0000u);        \
  const float F2 = __uint_as_float((u).y << 16);                \
  const float F3 = __uint_as_float((u).y & 0xffff0000u);        \
  const float F4 = __uint_as_float((u).z << 16);                \
  const float F5 = __uint_as_float((u).z & 0xffff0000u);        \
  const float F6 = __uint_as_float((u).w << 16);                \
  const float F7 = __uint_as_float((u).w & 0xffff0000u);

// ---------------------------------------------------------------- convert f32 -> bf16
__global__ void k_convert(const float* __restrict__ in, bf16* __restrict__ out, int n4) {
  int i = blockIdx.x * blockDim.x + threadIdx.x;
  if (i < n4) {
    float4 v = ((const float4*)in)[i];
    bf16 t[4] = {__float2bfloat16(v.x), __float2bfloat16(v.y),
                 __float2bfloat16(v.z), __float2bfloat16(v.w)};
    ((ushort4*)out)[i] = *(ushort4*)t;
  }
}

// ---------------------------------------------------------------- bf16 GEMM, C = A * Bw^T
// A: [M x KD] row-major bf16. Bw: [ncols x KD] row-major bf16 (i.e. B[k][n] = Bw[n][k]).
// 128x128 tile, BK=64, 4 waves each computing 64x64 (4x4 tiles of 16x16x32 MFMA).
template<int KD, bool OUTF32>
__global__ __launch_bounds__(256, 2)
void k_gemm(const bf16* __restrict__ A, const bf16* __restrict__ Bw,
            void* __restrict__ Cout, const float* __restrict__ bias, int ncols) {
  __shared__ bf16 As[128 * 64];
  __shared__ bf16 Bs[128 * 64];
  const int tid  = threadIdx.x;
  const int wave = tid >> 6, lane = tid & 63;
  const int quad = lane >> 4, l16 = lane & 15;
  const long row0 = (long)blockIdx.x * 128;
  const long col0 = (long)blockIdx.y * 128;
  const int wm = (wave & 1) * 64, wn = (wave >> 1) * 64;
  const int srow = lane >> 3;          // row within 8-row staging chunk
  const int skb  = (lane & 7) * 8;     // k-element offset (8 bf16 = 16B)

  f32x4 acc[4][4];
  const f32x4 z = {0.f, 0.f, 0.f, 0.f};
#pragma unroll
  for (int a = 0; a < 4; ++a)
#pragma unroll
    for (int b = 0; b < 4; ++b) acc[a][b] = z;

  for (int k0 = 0; k0 < KD; k0 += 64) {
#pragma unroll
    for (int i = 0; i < 4; ++i) {
      const int c = wave * 4 + i;          // chunk id, wave-uniform
      const int r = c * 8 + srow;          // tile row
      async_copy16(A  + (row0 + r) * KD + k0 + skb, (char*)As + c * 1024);
      async_copy16(Bw + (col0 + r) * KD + k0 + skb, (char*)Bs + c * 1024);
    }
    __syncthreads();
#pragma unroll
    for (int kk = 0; kk < 64; kk += 32) {
      bf16x8 af[4], bfr[4];
#pragma unroll
      for (int i = 0; i < 4; ++i)
        af[i] = *(const bf16x8*)(As + (wm + i * 16 + l16) * 64 + kk + quad * 8);
#pragma unroll
      for (int i = 0; i < 4; ++i)
        bfr[i] = *(const bf16x8*)(Bs + (wn + i * 16 + l16) * 64 + kk + quad * 8);
#pragma unroll
      for (int mi = 0; mi < 4; ++mi)
#pragma unroll
        for (int ni = 0; ni < 4; ++ni)
          acc[mi][ni] = __builtin_amdgcn_mfma_f32_16x16x32_bf16(af[mi], bfr[ni], acc[mi][ni], 0, 0, 0);
    }
    __syncthreads();
  }

  // epilogue: C/D layout col=lane&15, row=quad*4+reg
#pragma unroll
  for (int mi = 0; mi < 4; ++mi)
#pragma unroll
    for (int ni = 0; ni < 4; ++ni) {
      const long colg = col0 + wn + ni * 16 + l16;
#pragma unroll
      for (int r = 0; r < 4; ++r) {
        const long rowg = row0 + wm + mi * 16 + quad * 4 + r;
        const float v = acc[mi][ni][r];
        if (OUTF32) {
          ((float*)Cout)[rowg * ncols + colg] = v + bias[colg];
        } else {
          ((bf16*)Cout)[rowg * ncols + colg] = __float2bfloat16(v);
        }
      }
    }
}

// ---------------------------------------------------------------- spatial stats
// per (bt, h): kvs[m][d] = sum_n khat[n][m]*v[n][d]  (32x32), ks_sum[m] = sum_n khat[n][m]
// stats layout: [bt][h][1056] = 1024 kvs + 32 ks_sum, fp32
// ALSO writes khat (bf16) back in-place over the k slot of qkv (consumed by temporal).
__global__ __launch_bounds__(256)
void k_spatial_stats(bf16* __restrict__ qkv, float* __restrict__ stats) {
  const int bt = blockIdx.x, h = blockIdx.y;
  const int tid = threadIdx.x;
  const int wave = tid >> 6, lane = tid & 63;
  __shared__ float lk[256][36];   // khat, token-major, +pad
  __shared__ float lv[256][36];   // v
  const int mg = lane >> 3, dg = lane & 7;
  const int m0 = mg * 4, d0 = dg * 4;
  float acc[4][4] = {};
  float ssum[4] = {0.f, 0.f, 0.f, 0.f};

  for (int c = wave * 64; c < NN_; c += 256) {
    const size_t row = ((size_t)bt * NN_ + c + lane) * 768;
    bf16 kb[32], vb[32];
    const uint4* kp = (const uint4*)(qkv + row + 256 + h * 32);
    const uint4* vp = (const uint4*)(qkv + row + 512 + h * 32);
#pragma unroll
    for (int j = 0; j < 4; ++j) { ((uint4*)kb)[j] = kp[j]; ((uint4*)vb)[j] = vp[j]; }
    float kf[32]; float ss = 0.f;
#pragma unroll
    for (int j = 0; j < 32; ++j) { kf[j] = bf2f(kb[j]); ss += kf[j] * kf[j]; }
    const float sc = rsq_fast(ss);
#pragma unroll
    for (int j = 0; j < 32; ++j) kf[j] *= sc;
    // write khat back (bf16, 64B per token-head)
    ushort kh16[32];
#pragma unroll
    for (int j = 0; j < 32; ++j) kh16[j] = f2bfu(kf[j]);
    uint4* dstk = (uint4*)(qkv + row + 256 + h * 32);
#pragma unroll
    for (int j = 0; j < 4; ++j) dstk[j] = ((uint4*)kh16)[j];

    float vf[32];
#pragma unroll
    for (int j = 0; j < 32; ++j) vf[j] = bf2f(vb[j]);
    const int lrow = wave * 64 + lane;
#pragma unroll
    for (int j = 0; j < 8; ++j) {
      ((float4*)lk[lrow])[j] = ((float4*)kf)[j];
      ((float4*)lv[lrow])[j] = ((float4*)vf)[j];
    }
    __syncthreads();
#pragma unroll 2
    for (int t = 0; t < 64; ++t) {
      const int tr = wave * 64 + t;
      const float4 ka = *(const float4*)&lk[tr][m0];   // broadcast within wave (free)
      const float4 va = *(const float4*)&lv[tr][d0];
      const float km[4] = {ka.x, ka.y, ka.z, ka.w};
      const float vm[4] = {va.x, va.y, va.z, va.w};
#pragma unroll
      for (int i = 0; i < 4; ++i) {
        ssum[i] += km[i];
#pragma unroll
        for (int j = 0; j < 4; ++j) acc[i][j] += km[i] * vm[j];
      }
    }
    __syncthreads();
  }

  // cross-wave reduction via LDS (reuse lk storage: 4 x 1056 floats)
  float* rbuf = (float*)lk;
  float* wb = rbuf + wave * 1056;
#pragma unroll
  for (int i = 0; i < 4; ++i) {
    float4 o = {acc[i][0], acc[i][1], acc[i][2], acc[i][3]};
    *(float4*)&wb[(m0 + i) * 32 + d0] = o;
  }
  if (dg == 0) {
#pragma unroll
    for (int i = 0; i < 4; ++i) wb[1024 + m0 + i] = ssum[i];
  }
  __syncthreads();
  float* base = stats + ((size_t)bt * H_ + h) * 1056;
  for (int e = tid; e < 1056; e += 256)
    base[e] = rbuf[e] + rbuf[1056 + e] + rbuf[2112 + e] + rbuf[3168 + e];
}

// ---------------------------------------------------------------- spatial output (v5b, MFMA)
// block = (64-token chunk, bt), 256 threads (4 waves), 32 KB LDS.
// Phase 1 (transposed norm): thread = token, 2 heads each — L2 norm entirely in-lane
// (zero cross-lane ops), qhat -> swizzled LDS rows + global writeback (for temporal).
// Phase 2: wave w = 16-token tile; per h: num = qhat@kvs, den = qhat@(kss·1^T) via
// mfma_f32_16x16x32_bf16 with hi/lo bf16 split of the f32 stats (f32-class precision).
// Fragment mapping identical to k_gemm (A row=l16,k=quad*8+j; B col=l16,k=quad*8+j;
// C col=l16,row=quad*4+r).
#define SP_CHUNK 64
__global__ __launch_bounds__(256, 4)
void k_spatial_out(bf16* __restrict__ qkv, const float* __restrict__ stats,
                   bf16* __restrict__ concat) {
  const int c  = blockIdx.x;
  const int bt = blockIdx.y;
  const int tid = threadIdx.x;
  __shared__ bf16 qrows[8 * SP_CHUNK * 32];   // [h][tok][m], 16B-slot swizzled; 32 KB

  const size_t tok0 = (size_t)bt * NN_ + (size_t)c * SP_CHUNK;

  // ---- phase 1: per-token q-norm (thread = token, 2 heads) ----
  {
    const int tok = tid & (SP_CHUNK - 1);
    const int hp  = tid >> 6;            // 0..3
#pragma unroll
    for (int hh = 0; hh < 2; ++hh) {
      const int h = hp * 2 + hh;
      bf16* qp = qkv + (tok0 + tok) * 768 + h * 32;
      ushort qu[32];
#pragma unroll
      for (int j = 0; j < 4; ++j) ((uint4*)qu)[j] = ((const uint4*)qp)[j];
      float qf[32]; float ss = 0.f;
#pragma unroll
      for (int j = 0; j < 32; ++j) { qf[j] = bfu2f(qu[j]); ss = fmaf(qf[j], qf[j], ss); }
      const float sc = rsq_fast(ss);
      ushort qh[32];
#pragma unroll
      for (int j = 0; j < 32; ++j) qh[j] = f2bfu(qf[j] * sc);
      bf16* lbase = qrows + (h * SP_CHUNK + tok) * 32;
#pragma unroll
      for (int s = 0; s < 4; ++s) {
        ((uint4*)lbase)[s ^ (tok & 3)] = ((uint4*)qh)[s];   // swizzled LDS row
        ((uint4*)qp)[s] = ((uint4*)qh)[s];                  // qhat writeback (temporal)
      }
    }
  }
  __syncthreads();

  // ---- phase 2: MFMA per wave (tile = 16 tokens) ----
  const int wave = tid >> 6, lane = tid & 63;
  const int quad = lane >> 4, l16 = lane & 15;
  const int tA = wave * 16 + l16;        // A-frag token row
  const f32x4 z = {0.f, 0.f, 0.f, 0.f};

  for (int h = 0; h < 8; ++h) {
    // A fragment: qhat[tA][m = quad*8 + j] from swizzled LDS
    const bf16x8 af = *(const bf16x8*)(qrows + (h * SP_CHUNK + tA) * 32 + ((quad ^ (tA & 3)) * 8));

    const float* sb = stats + ((size_t)bt * H_ + h) * 1056;
    // B fragments (num): kvs[k = quad*8+j][d = dh*16 + l16], hi/lo bf16 split
    bf16x8 bn_hi[2], bn_lo[2];
#pragma unroll
    for (int dh = 0; dh < 2; ++dh) {
      ushort hi8[8], lo8[8];
#pragma unroll
      for (int j = 0; j < 8; ++j) {
        const float v = sb[(quad * 8 + j) * 32 + dh * 16 + l16];
        const ushort hu = f2bfu(v);
        hi8[j] = hu;
        lo8[j] = f2bfu(v - bfu2f(hu));
      }
      bn_hi[dh] = *(bf16x8*)hi8; bn_lo[dh] = *(bf16x8*)lo8;
    }
    // B fragment (den): kss[k] broadcast over cols, hi/lo split
    bf16x8 bd_hi, bd_lo;
    {
      ushort hi8[8], lo8[8];
#pragma unroll
      for (int j = 0; j < 8; ++j) {
        const float v = sb[1024 + quad * 8 + j];
        const ushort hu = f2bfu(v);
        hi8[j] = hu;
        lo8[j] = f2bfu(v - bfu2f(hu));
      }
      bd_hi = *(bf16x8*)hi8; bd_lo = *(bf16x8*)lo8;
    }

    f32x4 aN0 = z, aN1 = z, aD = z;
    aN0 = __builtin_amdgcn_mfma_f32_16x16x32_bf16(af, bn_hi[0], aN0, 0, 0, 0);
    aN0 = __builtin_amdgcn_mfma_f32_16x16x32_bf16(af, bn_lo[0], aN0, 0, 0, 0);
    aN1 = __builtin_amdgcn_mfma_f32_16x16x32_bf16(af, bn_hi[1], aN1, 0, 0, 0);
    aN1 = __builtin_amdgcn_mfma_f32_16x16x32_bf16(af, bn_lo[1], aN1, 0, 0, 0);
    aD  = __builtin_amdgcn_mfma_f32_16x16x32_bf16(af, bd_hi, aD, 0, 0, 0);
    aD  = __builtin_amdgcn_mfma_f32_16x16x32_bf16(af, bd_lo, aD, 0, 0, 0);

    // epilogue: C col = l16 (d within half), row = quad*4 + r (token within tile)
#pragma unroll
    for (int r = 0; r < 4; ++r) {
      const size_t tg = tok0 + wave * 16 + quad * 4 + r;
      const float rden = rcp_fast(fmaxf(aD[r] + 2048.f, 1e-5f));
#pragma unroll
      for (int dh = 0; dh < 2; ++dh) {
        const int d = dh * 16 + l16;
        const float vv = bf2f(qkv[tg * 768 + 512 + h * 32 + d]);
        const float num = (dh ? aN1[r] : aN0[r]) + 2048.f * vv;
        concat[tg * 512 + h * 32 + d] = __float2bfloat16(num * rden);
      }
    }
  }
}

// ---------------------------------------------------------------- temporal attention + output (v5)
// block = (n, b); thread = (h, d). khat/qhat are PRE-NORMALIZED (written in-place by the
// spatial kernels) -> no norm red32s here. Rows staged as bf16 via global_load_lds.
// kvcol[32] + kss[32] in registers; den fused into the num FMA loop. Zero cross-lane ops.
// Bare launch_bounds: live set needs ~112 VGPR; R3's (256,2) build allocated 64 and spilled.
__global__ __launch_bounds__(256)
void k_temporal_out(const bf16* __restrict__ qkv, bf16* __restrict__ concat) {
  const int n = blockIdx.x, b = blockIdx.y;
  const int tid = threadIdx.x;
  const int wave = tid >> 6, lane = tid & 63;
  const int h = tid >> 5, d = tid & 31;
  __shared__ uint4 rows4[384 * 4];   // 24 KB; row R = s*192 + t*8 + h (s: 0=khat,1=qhat), 64B each

  // stage khat+qhat rows: 384 rows x 64B; instr i covers rows [i*16, i*16+16)
  {
    const int rl = lane >> 2, p = lane & 3;
#pragma unroll
    for (int q = 0; q < 6; ++q) {
      const int i = wave * 6 + q;              // wave-uniform
      const int R = i * 16 + rl;
      const int s = (R >= 192) ? 1 : 0;
      const int tt = (R - s * 192) >> 3;
      const int hh = R & 7;
      const size_t tok = ((size_t)b * T_ + tt) * NN_ + n;
      const size_t e = tok * 768 + (s ? 0 : 256) + hh * 32 + p * 8;
      async_copy16(qkv + e, (char*)rows4 + i * 1024);
    }
  }

  // own v column (overlaps staging latency)
  const size_t basev = ((size_t)b * T_ * NN_ + n) * 768 + 512 + h * 32 + d;
  const size_t tstep = (size_t)NN_ * 768;
  float vf[T_];
#pragma unroll
  for (int t = 0; t < T_; ++t) vf[t] = bf2f(qkv[basev + t * tstep]);

  __syncthreads();

  // phase 2: kvcol[m] = sum_t khat[t][m]*v[t][d]; kss[m] = sum_t khat[t][m]
  float kvcol[32], kss[32];
#pragma unroll
  for (int m = 0; m < 32; ++m) { kvcol[m] = 0.f; kss[m] = 0.f; }
#pragma unroll
  for (int t = 0; t < T_; ++t) {
    const uint4* r4 = rows4 + (t * 8 + h) * 4;
    const float v = vf[t];
#pragma unroll
    for (int cc = 0; cc < 4; ++cc) {
      const uint4 u = r4[cc];
      const int m0 = cc * 8;
      UNPK8(u, f0, f1, f2, f3, f4, f5, f6, f7)
      kvcol[m0+0] = fmaf(f0, v, kvcol[m0+0]); kss[m0+0] += f0;
      kvcol[m0+1] = fmaf(f1, v, kvcol[m0+1]); kss[m0+1] += f1;
      kvcol[m0+2] = fmaf(f2, v, kvcol[m0+2]); kss[m0+2] += f2;
      kvcol[m0+3] = fmaf(f3, v, kvcol[m0+3]); kss[m0+3] += f3;
      kvcol[m0+4] = fmaf(f4, v, kvcol[m0+4]); kss[m0+4] += f4;
      kvcol[m0+5] = fmaf(f5, v, kvcol[m0+5]); kss[m0+5] += f5;
      kvcol[m0+6] = fmaf(f6, v, kvcol[m0+6]); kss[m0+6] += f6;
      kvcol[m0+7] = fmaf(f7, v, kvcol[m0+7]); kss[m0+7] += f7;
    }
  }

  // phase 3: num = qhat_row . kvcol + 24*v; den = qhat_row . kss + 24
#pragma unroll
  for (int t = 0; t < T_; ++t) {
    const uint4* r4 = rows4 + ((192 + t * 8 + h)) * 4;
    float num = 24.f * vf[t];
    float den = 24.f;
#pragma unroll
    for (int cc = 0; cc < 4; ++cc) {
      const uint4 u = r4[cc];
      const int m0 = cc * 8;
      UNPK8(u, f0, f1, f2, f3, f4, f5, f6, f7)
      num = fmaf(f0, kvcol[m0+0], num); den = fmaf(f0, kss[m0+0], den);
      num = fmaf(f1, kvcol[m0+1], num); den = fmaf(f1, kss[m0+1], den);
      num = fmaf(f2, kvcol[m0+2], num); den = fmaf(f2, kss[m0+2], den);
      num = fmaf(f3, kvcol[m0+3], num); den = fmaf(f3, kss[m0+3], den);
      num = fmaf(f4, kvcol[m0+4], num); den = fmaf(f4, kss[m0+4], den);
      num = fmaf(f5, kvcol[m0+5], num); den = fmaf(f5, kss[m0+5], den);
      num = fmaf(f6, kvcol[m0+6], num); den = fmaf(f6, kss[m0+6], den);
      num = fmaf(f7, kvcol[m0+7], num); den = fmaf(f7, kss[m0+7], den);
    }
    den = fmaxf(den, 1e-5f);
    const size_t tok = (size_t)(b * T_ + t) * NN_ + n;
    concat[tok * 512 + 256 + h * 32 + d] = __float2bfloat16(num * rcp_fast(den));
  }
}

// ---------------------------------------------------------------- launch
extern "C" void kernel_launch(void* const* d_in, const int* in_sizes, int n_in,
                              void* d_out, int out_size, void* d_ws, size_t ws_size,
                              hipStream_t stream) {
  (void)in_sizes; (void)n_in; (void)out_size; (void)ws_size;
  const float* x     = (const float*)d_in[0];
  const float* w_qkv = (const float*)d_in[1];
  const float* w_out = (const float*)d_in[2];
  const float* b_out = (const float*)d_in[3];
  float* out = (float*)d_out;
  char* ws = (char*)d_ws;

  // workspace layout (bytes); concat aliases x_bf16 (dead after K1)
  bf16* concat = (bf16*)(ws);                       // 201,326,592 B (196608*512*2)
  bf16* xb     = (bf16*)(ws);                       // 100,663,296 B (aliased)
  bf16* qkv    = (bf16*)(ws + 201326592);           // 301,989,888 B
  float* stats = (float*)(ws + 503316480);          //   3,244,032 B
  bf16* wqkvb  = (bf16*)(ws + 506560512);           //     393,216 B
  bf16* woutb  = (bf16*)(ws + 506953728);           //     262,144 B
  // total: 507,215,872 B

  // converts
  k_convert<<<(MTOK * D_ / 4 + 255) / 256, 256, 0, stream>>>(x, xb, MTOK * D_ / 4);
  k_convert<<<(768 * 256 / 4 + 255) / 256, 256, 0, stream>>>(w_qkv, wqkvb, 768 * 256 / 4);
  k_convert<<<(256 * 512 / 4 + 255) / 256, 256, 0, stream>>>(w_out, woutb, 256 * 512 / 4);

  // qkv = x @ w_qkv^T   (M=196608, N=768, K=256)
  k_gemm<256, false><<<dim3(MTOK / 128, 768 / 128), 256, 0, stream>>>(xb, wqkvb, qkv, nullptr, 768);

  // spatial stats over N (also writes khat in-place)
  k_spatial_stats<<<dim3(BT_, H_), 256, 0, stream>>>(qkv, stats);

  // spatial output (also writes qhat in-place), then temporal (consumes khat/qhat)
  k_spatial_out<<<dim3(NN_ / SP_CHUNK, BT_), 256, 0, stream>>>(qkv, stats, concat);
  k_temporal_out<<<dim3(NN_, B_), 256, 0, stream>>>(qkv, concat);

  // final: out = concat @ w_out^T + b_out   (M=196608, N=256, K=512)
  k_gemm<512, true><<<dim3(MTOK / 128, 256 / 128), 256, 0, stream>>>(concat, woutb, out, b_out, 256);
}